// Round 5
// baseline (52.810 us; speedup 1.0000x reference)
//
#include <hip/hip_runtime.h>

// Weighted moving average, causal, weights [1..W], W=32.
// x: [B=32, T=8192, C=128] f32 -> out same shape.
//
// Recurrence per channel stream:
//   N[t] = N[t-1] - S[t-1] + W*x[t]      (weighted numerator)
//   S[t] = S[t-1] - x[t-W] + x[t]        (window sum)
// x[t-W] kept in a 32-deep register ring buffer (static indexing, full unroll).
//
// Each thread: 2 adjacent channels (8 B/lane), SEG=64 T-steps.
// SEG=64 (vs 128) doubles resident waves (16/CU) to hide HBM latency;
// warm-up reads overlap the previous segment streamed by a sibling thread
// in the same block -> L2-hit.

typedef float f32x2 __attribute__((ext_vector_type(2)));

constexpr int W    = 32;
constexpr int B    = 32;
constexpr int T    = 8192;
constexpr int C    = 128;
constexpr int CP   = C / 2;        // channel pairs = 64
constexpr int SEG  = 64;           // T elements per thread (multiple of W)
constexpr int NSEG = T / SEG;      // 128

__global__ __launch_bounds__(256)
void wma_kernel(const float* __restrict__ x, float* __restrict__ out) {
    int gtid = blockIdx.x * blockDim.x + threadIdx.x;
    int p    = gtid % CP;          // channel pair
    int rest = gtid / CP;
    int seg  = rest % NSEG;
    int b    = rest / NSEG;
    if (b >= B) return;

    const int t0 = seg * SEG;
    const f32x2* px = (const f32x2*)(x   + ((size_t)b * T + t0) * C) + p;
    f32x2*       po = (f32x2*)      (out + ((size_t)b * T + t0) * C) + p;

    f32x2 hist[W];                 // hist[i] = x[t-W+...] for current chunk
    float Sx = 0.f, Sy = 0.f, Nx = 0.f, Ny = 0.f;
    int startChunk = 0;

    if (t0 == 0) {
        // Partial-window start: zero history, per-step denominator.
        #pragma unroll
        for (int i = 0; i < W; ++i) hist[i] = (f32x2){0.f, 0.f};
        #pragma unroll
        for (int i = 0; i < W; ++i) {
            f32x2 xn = px[i * CP];
            Nx = Nx - Sx + 32.0f * xn.x;
            Ny = Ny - Sy + 32.0f * xn.y;
            Sx = Sx - hist[i].x + xn.x;
            Sy = Sy - hist[i].y + xn.y;
            hist[i] = xn;
            // denom[t] = 528 - (31-t)(32-t)/2, compile-time per unrolled i
            const float invd = 1.0f / (float)(528 - (31 - i) * (32 - i) / 2);
            f32x2 o = {Nx * invd, Ny * invd};
            __builtin_nontemporal_store(o, &po[i * CP]);
        }
        startChunk = 1;
    } else {
        // Warm-up: read the 32 samples before t0, build S and N at t0-1.
        #pragma unroll
        for (int i = 0; i < W; ++i) hist[i] = px[(i - W) * CP];
        #pragma unroll
        for (int i = 0; i < W; ++i) {
            Sx += hist[i].x;
            Sy += hist[i].y;
            Nx += (float)(i + 1) * hist[i].x;
            Ny += (float)(i + 1) * hist[i].y;
        }
    }

    const float invD = 1.0f / 528.0f;   // sum(1..32)
    for (int ch = startChunk; ch < SEG / W; ++ch) {
        const f32x2* pxc = px + (size_t)ch * W * CP;
        f32x2*       poc = po + (size_t)ch * W * CP;
        #pragma unroll
        for (int i = 0; i < W; ++i) {
            f32x2 xn = pxc[i * CP];
            Nx = Nx - Sx + 32.0f * xn.x;
            Ny = Ny - Sy + 32.0f * xn.y;
            Sx = Sx - hist[i].x + xn.x;   // hist[i] == x[t-W] (aligned chunks)
            Sy = Sy - hist[i].y + xn.y;
            hist[i] = xn;
            f32x2 o = {Nx * invD, Ny * invD};
            __builtin_nontemporal_store(o, &poc[i * CP]);
        }
    }
}

extern "C" void kernel_launch(void* const* d_in, const int* in_sizes, int n_in,
                              void* d_out, int out_size, void* d_ws, size_t ws_size,
                              hipStream_t stream) {
    const float* x = (const float*)d_in[0];
    // d_in[1] = weights [1..32], d_in[2] = window_size (=32): baked in.
    float* out = (float*)d_out;

    const int total_threads = B * CP * NSEG;   // 262144
    dim3 grid(total_threads / 256), block(256);
    hipLaunchKernelGGL(wma_kernel, grid, block, 0, stream, x, out);
}

// Round 6
// 49.863 us; speedup vs baseline: 1.0591x; 1.0591x over previous
//
#include <hip/hip_runtime.h>

// Weighted moving average, causal, weights [1..W], W=32.
// x: [B=32, T=8192, C=128] f32 -> out same shape.
//
// Recurrence per channel stream:
//   N[t] = N[t-1] - S[t-1] + W*x[t]      (weighted numerator)
//   S[t] = S[t-1] - x[t-W] + x[t]        (window sum)
// x[t-W] kept in a 32-deep register ring buffer (static indexing, full unroll).
//
// Round 6: FOUR adjacent channels per thread (16 B/lane, the coalescing
// sweet spot the 6.3 TB/s copy ceiling is measured at). SEG=128 keeps the
// 1.25x warm-up factor. Grid = 256 blocks = 1/CU, 4 waves/CU.
// launch_bounds(256,1): hist[32] f32x4 = 128 VGPRs, allow up to 512, no spill.

typedef float f32x4 __attribute__((ext_vector_type(4)));

constexpr int W    = 32;
constexpr int B    = 32;
constexpr int T    = 8192;
constexpr int C    = 128;
constexpr int CQ   = C / 4;        // channel quads = 32
constexpr int SEG  = 128;          // T elements per thread (multiple of W)
constexpr int NSEG = T / SEG;      // 64

__global__ __launch_bounds__(256, 1)
void wma_kernel(const float* __restrict__ x, float* __restrict__ out) {
    int gtid = blockIdx.x * blockDim.x + threadIdx.x;
    int p    = gtid % CQ;          // channel quad
    int rest = gtid / CQ;
    int seg  = rest % NSEG;
    int b    = rest / NSEG;

    const int t0 = seg * SEG;
    const f32x4* px = (const f32x4*)(x   + ((size_t)b * T + t0) * C) + p;
    f32x4*       po = (f32x4*)      (out + ((size_t)b * T + t0) * C) + p;

    f32x4 hist[W];                 // hist[i] = x[t-W+...] for current chunk
    f32x4 S = (f32x4)(0.f), N = (f32x4)(0.f);
    int startChunk = 0;

    if (t0 == 0) {
        // Partial-window start: zero history, per-step denominator.
        #pragma unroll
        for (int i = 0; i < W; ++i) hist[i] = (f32x4)(0.f);
        #pragma unroll
        for (int i = 0; i < W; ++i) {
            f32x4 xn = px[i * CQ];
            N = N - S + 32.0f * xn;
            S = S - hist[i] + xn;
            hist[i] = xn;
            // denom[t] = 528 - (31-t)(32-t)/2, compile-time per unrolled i
            const float invd = 1.0f / (float)(528 - (31 - i) * (32 - i) / 2);
            f32x4 o = N * invd;
            __builtin_nontemporal_store(o, &po[i * CQ]);
        }
        startChunk = 1;
    } else {
        // Warm-up: read the 32 samples before t0, build S and N at t0-1.
        #pragma unroll
        for (int i = 0; i < W; ++i) hist[i] = px[(i - W) * CQ];
        #pragma unroll
        for (int i = 0; i < W; ++i) {
            S += hist[i];
            N += (float)(i + 1) * hist[i];
        }
    }

    const float invD = 1.0f / 528.0f;   // sum(1..32)
    for (int ch = startChunk; ch < SEG / W; ++ch) {
        const f32x4* pxc = px + (size_t)ch * W * CQ;
        f32x4*       poc = po + (size_t)ch * W * CQ;
        #pragma unroll
        for (int i = 0; i < W; ++i) {
            f32x4 xn = pxc[i * CQ];
            N = N - S + 32.0f * xn;
            S = S - hist[i] + xn;   // hist[i] == x[t-W] (aligned chunks)
            hist[i] = xn;
            f32x4 o = N * invD;
            __builtin_nontemporal_store(o, &poc[i * CQ]);
        }
    }
}

extern "C" void kernel_launch(void* const* d_in, const int* in_sizes, int n_in,
                              void* d_out, int out_size, void* d_ws, size_t ws_size,
                              hipStream_t stream) {
    const float* x = (const float*)d_in[0];
    // d_in[1] = weights [1..32], d_in[2] = window_size (=32): baked in.
    float* out = (float*)d_out;

    const int total_threads = B * CQ * NSEG;   // 65536
    dim3 grid(total_threads / 256), block(256);
    hipLaunchKernelGGL(wma_kernel, grid, block, 0, stream, x, out);
}

// Round 7
// 49.006 us; speedup vs baseline: 1.0776x; 1.0175x over previous
//
#include <hip/hip_runtime.h>

// Weighted moving average, causal, weights [1..W], W=32.
// x: [B=32, T=8192, C=128] f32 -> out same shape.
//
// Recurrence: N[t] = N[t-1] - S[t-1] + W*x[t];  S[t] = S[t-1] - x[t-W] + x[t]
//
// Round 7: rolling software pipeline. hist for chunk k == chunk k-1's load
// buffer, so double-buffer A/B and refill prev[i] with chunk k+1's load
// right after step i consumes it. Next-chunk loads issue interleaved 1:1
// with this chunk's compute+stores -> smooth read/write mix instead of
// phase-aligned load-burst/store-burst (the R2-R6 49us wall).
// float2/lane, SEG=128, fully unrolled, all indices static.

typedef float f32x2 __attribute__((ext_vector_type(2)));

constexpr int W    = 32;
constexpr int B    = 32;
constexpr int T    = 8192;
constexpr int C    = 128;
constexpr int CP   = C / 2;        // channel pairs = 64
constexpr int SEG  = 128;          // T elements per thread (4 chunks of W)
constexpr int NSEG = T / SEG;      // 64

// One chunk: consume CUR (this chunk's x), PRV (last chunk's x = hist),
// store to element offset STO; if PF, prefetch from element offset LDO
// into PRV[i] right after PRV[i] is consumed.
#define CHUNK_BODY(CUR, PRV, PF, LDO, STO)                          \
    _Pragma("unroll")                                               \
    for (int i = 0; i < W; ++i) {                                   \
        f32x2 xn = CUR[i];                                          \
        N2 = N2 - S2 + 32.0f * xn;                                  \
        S2 = S2 - PRV[i] + xn;                                      \
        f32x2 o = N2 * invD;                                        \
        __builtin_nontemporal_store(o, &po[(STO) + i * CP]);        \
        if (PF) PRV[i] = px[(LDO) + i * CP];                        \
    }

__global__ __launch_bounds__(256)
void wma_kernel(const float* __restrict__ x, float* __restrict__ out) {
    int gtid = blockIdx.x * blockDim.x + threadIdx.x;
    int p    = gtid % CP;          // channel pair
    int rest = gtid / CP;
    int seg  = rest % NSEG;
    int b    = rest / NSEG;

    const int t0 = seg * SEG;
    const f32x2* px = (const f32x2*)(x   + ((size_t)b * T + t0) * C) + p;
    f32x2*       po = (f32x2*)      (out + ((size_t)b * T + t0) * C) + p;

    f32x2 A[W], Bf[W];             // double buffer: cur / prev(hist)
    f32x2 S2 = (f32x2)(0.f), N2 = (f32x2)(0.f);
    const float invD = 1.0f / 528.0f;   // sum(1..32)

    if (t0 == 0) {
        // chunk0 loads first (longest lead), prev = zeros.
        #pragma unroll
        for (int i = 0; i < W; ++i) A[i]  = px[i * CP];
        #pragma unroll
        for (int i = 0; i < W; ++i) Bf[i] = (f32x2)(0.f);
        // chunk0: per-step partial-window denominator; prefetch chunk1 -> Bf.
        #pragma unroll
        for (int i = 0; i < W; ++i) {
            f32x2 xn = A[i];
            N2 = N2 - S2 + 32.0f * xn;
            S2 = S2 - Bf[i] + xn;
            // denom[t] = 528 - (31-t)(32-t)/2, compile-time per unrolled i
            const float invd = 1.0f / (float)(528 - (31 - i) * (32 - i) / 2);
            f32x2 o = N2 * invd;
            __builtin_nontemporal_store(o, &po[i * CP]);
            Bf[i] = px[(1 * W * CP / CP * CP) / CP * 0 + (W * CP) / CP * CP * 0 + (W + i) * CP - i * CP + i * CP];
        }
    } else {
        // Warm-up (chunk -1) into Bf, chunk0 into A; build S,N from Bf.
        #pragma unroll
        for (int i = 0; i < W; ++i) Bf[i] = px[(i - W) * CP];
        #pragma unroll
        for (int i = 0; i < W; ++i) A[i]  = px[i * CP];
        #pragma unroll
        for (int i = 0; i < W; ++i) {
            S2 += Bf[i];
            N2 += (float)(i + 1) * Bf[i];
        }
        // chunk0: steady denominator; prefetch chunk1 -> Bf.
        CHUNK_BODY(A, Bf, true, 1 * W * CP, 0 * W * CP)
    }

    // state here (both paths): Bf = chunk1 data, A = chunk0 data (hist).
    CHUNK_BODY(Bf, A,  true,  2 * W * CP, 1 * W * CP)
    CHUNK_BODY(A,  Bf, true,  3 * W * CP, 2 * W * CP)
    CHUNK_BODY(Bf, A,  false, 0,          3 * W * CP)
}

extern "C" void kernel_launch(void* const* d_in, const int* in_sizes, int n_in,
                              void* d_out, int out_size, void* d_ws, size_t ws_size,
                              hipStream_t stream) {
    const float* x = (const float*)d_in[0];
    // d_in[1] = weights [1..32], d_in[2] = window_size (=32): baked in.
    float* out = (float*)d_out;
    const int total_threads = B * CP * NSEG;   // 131072
    dim3 grid(total_threads / 256), block(256);
    hipLaunchKernelGGL(wma_kernel, grid, block, 0, stream, x, out);
}